// Round 1
// 285.596 us; speedup vs baseline: 1.1205x; 1.1205x over previous
//
#include <hip/hip_runtime.h>
#include <hip/hip_bf16.h>

typedef __bf16 bf16;
typedef __attribute__((ext_vector_type(8))) __bf16 bf16x8;
typedef __attribute__((ext_vector_type(4))) __bf16 bf16x4;
typedef __attribute__((ext_vector_type(2))) __bf16 bf16x2;
typedef __attribute__((ext_vector_type(4))) float f32x4;
typedef __attribute__((ext_vector_type(2))) unsigned int u32x2;
typedef __attribute__((ext_vector_type(4))) unsigned int u32x4;

#define MFMA16(a, b, c) __builtin_amdgcn_mfma_f32_16x16x32_bf16((a), (b), (c), 0, 0, 0)
#define SM_SCALE 0.18033688011112043f  // (1/8) * log2(e), folded into q at GEMM epilogue

__device__ __forceinline__ void gld_lds16(const bf16* g, bf16* l) {
    __builtin_amdgcn_global_load_lds((const __attribute__((address_space(1))) void*)g,
                                     (__attribute__((address_space(3))) void*)l, 16, 0, 0);
}

// ---------------- f32 -> bf16 convert (x) ----------------
__global__ __launch_bounds__(256) void cvt_x(const float* __restrict__ in,
                                             bf16* __restrict__ outb, int n) {
    int i = (blockIdx.x * 256 + threadIdx.x) * 4;
    if (i + 3 < n) {
        const float4 v = *(const float4*)(in + i);
        bf16x4 o = {(bf16)v.x, (bf16)v.y, (bf16)v.z, (bf16)v.w};
        *(bf16x4*)(outb + i) = o;
    }
}

// ---------------- W [K][N] f32 -> Wt [N][K] bf16, 3 weights in one launch ----------------
__global__ __launch_bounds__(256) void transpose_w3(const float* __restrict__ W0,
                                                    const float* __restrict__ W1,
                                                    const float* __restrict__ W2,
                                                    bf16* __restrict__ Wt) {
    const float* W = (blockIdx.z == 0) ? W0 : ((blockIdx.z == 1) ? W1 : W2);
    bf16* dst = Wt + (size_t)blockIdx.z * 1024 * 1024;
    __shared__ float tile[64][65];
    const int r0 = blockIdx.y * 64;  // k
    const int c0 = blockIdx.x * 64;  // n
    const int tid = threadIdx.x;
    for (int i = tid; i < 4096; i += 256) {
        int r = i >> 6, cc = i & 63;
        tile[r][cc] = W[(size_t)(r0 + r) * 1024 + c0 + cc];
    }
    __syncthreads();
    for (int i = tid; i < 4096; i += 256) {
        int n = i >> 6, k = i & 63;
        dst[(size_t)(c0 + n) * 1024 + r0 + k] = (bf16)tile[k][n];
    }
}

// ---------------- GEMM: C = A[M,K] @ Bt[N,K]^T + bias ----------------
// MODE 0: fused QKV (N=3072): q output pre-scaled by SM_SCALE; v written
//         transposed into Vt[bh][d][t].   MODE 1: f32 output, N=1024.
template <int MODE>
__global__ __launch_bounds__(256) void gemm_bt(const bf16* __restrict__ A,
                                               const bf16* __restrict__ Bt,
                                               const float* __restrict__ b0,
                                               const float* __restrict__ b1,
                                               const float* __restrict__ b2,
                                               void* __restrict__ out0,
                                               void* __restrict__ out1,
                                               void* __restrict__ out2,
                                               int M, int N, int K) {
    __shared__ alignas(16) bf16 As[128 * 32];
    __shared__ alignas(16) bf16 Bs[128 * 32];
    const int tid = threadIdx.x;
    const int wave = tid >> 6, lane = tid & 63;
    const int quad = lane >> 4, l16 = lane & 15;
    const int m0 = blockIdx.y * 128, n0 = blockIdx.x * 128;
    const int wm = (wave & 1) * 64, wn = (wave >> 1) * 64;

    f32x4 acc[4][4] = {};

    const int srow = lane >> 2, scol = (lane & 3) * 8;
    const bf16* ga = A + (size_t)(m0 + wave * 32 + srow) * K + scol;
    const bf16* gb = Bt + (size_t)(n0 + wave * 32 + srow) * K + scol;
    bf16* la = &As[(wave * 32) * 32];
    bf16* lb = &Bs[(wave * 32) * 32];

    for (int k0 = 0; k0 < K; k0 += 32) {
        __syncthreads();
        gld_lds16(ga + k0, la);
        gld_lds16(ga + k0 + (size_t)16 * K, la + 16 * 32);
        gld_lds16(gb + k0, lb);
        gld_lds16(gb + k0 + (size_t)16 * K, lb + 16 * 32);
        __syncthreads();
        bf16x8 af[4], bfr[4];
#pragma unroll
        for (int mi = 0; mi < 4; mi++)
            af[mi] = *(const bf16x8*)&As[(wm + mi * 16 + l16) * 32 + quad * 8];
#pragma unroll
        for (int ni = 0; ni < 4; ni++)
            bfr[ni] = *(const bf16x8*)&Bs[(wn + ni * 16 + l16) * 32 + quad * 8];
#pragma unroll
        for (int mi = 0; mi < 4; mi++)
#pragma unroll
            for (int ni = 0; ni < 4; ni++)
                acc[mi][ni] = MFMA16(af[mi], bfr[ni], acc[mi][ni]);
    }

    if (MODE == 0) {
        const int sel = n0 >> 10;  // 0=q, 1=k, 2=v
        const int nl0 = (n0 & 1023) + wn;
        const float* bias = (sel == 0) ? b0 : ((sel == 1) ? b1 : b2);
        const float qscale = (sel == 0) ? SM_SCALE : 1.0f;
        if (sel < 2) {
            bf16* Cp = (bf16*)((sel == 0) ? out0 : out1);
#pragma unroll
            for (int mi = 0; mi < 4; mi++) {
                const int mbase = m0 + wm + mi * 16 + quad * 4;
#pragma unroll
                for (int ni = 0; ni < 4; ni++) {
                    const int nl = nl0 + ni * 16 + l16;
                    const float bv = bias[nl];
#pragma unroll
                    for (int r = 0; r < 4; r++)
                        Cp[(size_t)(mbase + r) * 1024 + nl] =
                            (bf16)((acc[mi][ni][r] + bv) * qscale);
                }
            }
        } else {
            bf16* Vt = (bf16*)out2;
            const int b = m0 >> 11;  // 2048 rows/batch; 128-row block never straddles
#pragma unroll
            for (int ni = 0; ni < 4; ni++) {
                const int nl = nl0 + ni * 16 + l16;
                const int h = nl >> 6, d = nl & 63;
                const float bv = bias[nl];
                bf16* dst = Vt + ((size_t)(b * 16 + h) * 64 + d) * 2048;
#pragma unroll
                for (int mi = 0; mi < 4; mi++) {
                    const int t0 = (m0 + wm + mi * 16 + quad * 4) & 2047;  // batch-local t
                    bf16x4 w = {(bf16)(acc[mi][ni][0] + bv), (bf16)(acc[mi][ni][1] + bv),
                                (bf16)(acc[mi][ni][2] + bv), (bf16)(acc[mi][ni][3] + bv)};
                    *(bf16x4*)&dst[t0] = w;
                }
            }
        }
    } else {
        float* Cp = (float*)out0;
#pragma unroll
        for (int mi = 0; mi < 4; mi++) {
            const int mbase = m0 + wm + mi * 16 + quad * 4;
#pragma unroll
            for (int ni = 0; ni < 4; ni++) {
                const int n = n0 + wn + ni * 16 + l16;
                const float bv = b0[n];
#pragma unroll
                for (int r = 0; r < 4; r++)
                    Cp[(size_t)(mbase + r) * 1024 + n] = acc[mi][ni][r] + bv;
            }
        }
    }
}

// ---------------- flash attention, causal, hs=64 ----------------
// 64-q causal pairing: block j does q-strips (31-j) then j -> every block
// exactly 33 KV-tiles (uniform), 1024 blocks. R8 changes vs R7:
//  * P never touches LDS: swapped-QK acc (st[j][r] = S[kv=j*16+quad*4+r][q=l16])
//    is cvt_pk'd to bf16 pairs and redistributed to the PV B-fragment layout
//    (P[kv=ks*32+quad*8+e][q=l16]) with v_permlane32_swap + v_permlane16_swap
//    (pure-VALU cross-quad moves; l16==q is invariant under both). Kills the
//    per-tile P ds_write->ds_read lgkm round trip + its bank conflicts.
//  * Ps LDS array dropped; epilogue transpose reuses the idle KV dbuf half
//    (its readers finished 2 barriers ago; per-wave disjoint 16-row slices).
//    LDS 46080 -> 36864 B => 4 blocks/CU resident; grid 1024 = 4/CU => all
//    blocks resident for the whole dispatch, no 1-resident tail phase.
//  * XCD-aware bijective swizzle: all 16 j-blocks of a (b,h) on one XCD
//    (8 bh/XCD) so K/V panels stay L2-local instead of 8x cross-XCD fetch.
template <bool NEEDMASK>
__device__ __forceinline__ void softmax_reg(const f32x4* st, float& l_i, bf16x8* pf,
                                            int qrel) {
    unsigned int p[4][2];
#pragma unroll
    for (int j = 0; j < 4; j++) {
        float pv[4];
#pragma unroll
        for (int r = 0; r < 4; r++) {
            float s = st[j][r];
            if (NEEDMASK && (j * 16 + r > qrel)) s = -1e30f;
            const float e = exp2f(s);
            l_i += e;
            pv[r] = e;
        }
        bf16x2 w0 = {(bf16)pv[0], (bf16)pv[1]};  // v_cvt_pk_bf16_f32 (compiler-fused)
        bf16x2 w1 = {(bf16)pv[2], (bf16)pv[3]};
        p[j][0] = __builtin_bit_cast(unsigned int, w0);
        p[j][1] = __builtin_bit_cast(unsigned int, w1);
    }
    // Redistribute acc layout -> B-frag layout. Target lane (quad t, l16) reg
    // e2 needs p[2ks + (t>>1)][e2&1] from source quad 2*(t&1) + (e2>>1):
    //   permlane32_swap(x,y) -> u={x.lo,y.lo}, v={x.hi,y.hi}   (reg-sel by t>>1)
    //   permlane16_swap(u,v) -> u'=(e2_1=0 frag), v'=(e2_1=1 frag)
#pragma unroll
    for (int ks = 0; ks < 2; ks++) {
        unsigned int q4[4];
#pragma unroll
        for (int h = 0; h < 2; h++) {
            u32x2 s32 = __builtin_amdgcn_permlane32_swap(p[2 * ks][h], p[2 * ks + 1][h],
                                                         false, false);
            u32x2 s16 = __builtin_amdgcn_permlane16_swap(s32[0], s32[1], false, false);
            q4[h] = s16[0];      // e2 = h     (kv ofs 2h, 2h+1)
            q4[2 + h] = s16[1];  // e2 = 2+h   (kv ofs 4+2h, 5+2h)
        }
        u32x4 qq = {q4[0], q4[1], q4[2], q4[3]};
        pf[ks] = __builtin_bit_cast(bf16x8, qq);
    }
}

__global__ __launch_bounds__(256, 4) void attn(const bf16* __restrict__ Q,
                                               const bf16* __restrict__ Kg,
                                               const bf16* __restrict__ Vt,
                                               bf16* __restrict__ O) {
    // bijective XCD swizzle: lin%8 = XCD (round-robin dispatch); give each XCD
    // 8 whole (b,h) heads with all 16 of their j-blocks.
    const int lin = blockIdx.y * 16 + blockIdx.x;
    const int bh = (lin & 7) * 8 + ((lin >> 3) & 7);
    const int jb = lin >> 6;  // [0,16)
    const int b = bh >> 4, h = bh & 15;
    const int tid = threadIdx.x;
    const int wave = tid >> 6, lane = tid & 63;
    const int quad = lane >> 4, l16 = lane & 15;

    __shared__ alignas(16) bf16 KVs[2 * 128 * 72];  // dbuf; per buf: rows 0-63 K, 64-127 V^T

    const bf16* Kbase = Kg + ((size_t)b * 2048) * 1024 + h * 64;
    const bf16* Vbase = Vt + (size_t)bh * 64 * 2048;

    const int ra = tid >> 3, oa = (tid & 7) * 8;

#pragma unroll 1
    for (int phase = 0; phase < 2; phase++) {
        // causal pairing at 64-q granularity: strip (31-j) then j -> 33 tiles total
        const int qs = (phase == 0) ? (31 - jb) : jb;
        const int q0 = qs * 64;
        const bf16* Qbase = Q + ((size_t)(b * 2048 + q0)) * 1024 + h * 64;

        // Q fragments in registers (pre-scaled by SM_SCALE at the QKV GEMM)
        bf16x8 qf[2];
#pragma unroll
        for (int ks = 0; ks < 2; ks++)
            qf[ks] = *(const bf16x8*)&Qbase[(size_t)(wave * 16 + l16) * 1024 + ks * 32 + quad * 8];

        float l_i = 0.f;
        f32x4 ot[4] = {};
        const int ntiles = qs + 1;
        const int qrel = wave * 16 + l16 - quad * 4;  // for diagonal-tile mask

        // rolling staging pointers (advance one 64-kv tile per iteration)
        const bf16* pK0 = Kbase + (size_t)ra * 1024 + oa;
        const bf16* pK1 = Kbase + (size_t)(ra + 32) * 1024 + oa;
        const bf16* pV0 = Vbase + (size_t)ra * 2048 + oa;
        const bf16* pV1 = Vbase + (size_t)(ra + 32) * 2048 + oa;

        bf16x8 rc0 = *(const bf16x8*)pK0, rc1 = *(const bf16x8*)pK1;
        bf16x8 rc2 = *(const bf16x8*)pV0, rc3 = *(const bf16x8*)pV1;
        bf16x8 rn0, rn1, rn2, rn3;

#pragma unroll 1
        for (int tk = 0; tk < ntiles; tk++) {
            if (tk + 1 < ntiles) {  // prefetch next tile (flies across barrier+compute)
                rn0 = *(const bf16x8*)(pK0 + 64 * 1024);
                rn1 = *(const bf16x8*)(pK1 + 64 * 1024);
                rn2 = *(const bf16x8*)(pV0 + 64);
                rn3 = *(const bf16x8*)(pV1 + 64);
                pK0 += 64 * 1024; pK1 += 64 * 1024; pV0 += 64; pV1 += 64;
            }
            bf16* buf = &KVs[(tk & 1) * (128 * 72)];
            *(bf16x8*)&buf[ra * 72 + oa] = rc0;
            *(bf16x8*)&buf[(ra + 32) * 72 + oa] = rc1;
            *(bf16x8*)&buf[(64 + ra) * 72 + oa] = rc2;
            *(bf16x8*)&buf[(64 + ra + 32) * 72 + oa] = rc3;
            __syncthreads();  // sole barrier: buf writes visible; other buf's readers done

            // S^T = K . Q^T (every wave active every tile of its phase)
            f32x4 st[4] = {};
#pragma unroll
            for (int ks = 0; ks < 2; ks++)
#pragma unroll
                for (int j = 0; j < 4; j++) {
                    const bf16x8 kf =
                        *(const bf16x8*)&buf[(j * 16 + l16) * 72 + ks * 32 + quad * 8];
                    st[j] = MFMA16(kf, qf[ks], st[j]);
                }

            // softmax + in-register P redistribution (no LDS round trip)
            bf16x8 pf[2];
            if (tk == ntiles - 1)
                softmax_reg<true>(st, l_i, pf, qrel);
            else
                softmax_reg<false>(st, l_i, pf, qrel);

            // O^T += V^T . P^T (P fragment straight from registers)
#pragma unroll
            for (int ks = 0; ks < 2; ks++)
#pragma unroll
                for (int db = 0; db < 4; db++) {
                    const bf16x8 vf =
                        *(const bf16x8*)&buf[(64 + db * 16 + l16) * 72 + ks * 32 + quad * 8];
                    ot[db] = MFMA16(vf, pf[ks], ot[db]);
                }
            rc0 = rn0; rc1 = rn1; rc2 = rn2; rc3 = rn3;
        }

        // l reduction across the 4 quads (kv was distributed over quads)
        l_i += __shfl_xor(l_i, 16, 64);
        l_i += __shfl_xor(l_i, 32, 64);

        // epilogue: O^T regs -> transpose staging in the idle KV dbuf half
        // (last tile read buf[(ntiles-1)&1]; buf[ntiles&1]'s readers finished
        //  before that tile's barrier; each wave uses its own 16-row slice)
        bf16* ep = &KVs[(ntiles & 1) * (128 * 72) + (wave * 16) * 72];
        const float inv = 1.f / l_i;
#pragma unroll
        for (int db = 0; db < 4; db++) {
            bf16x4 w = {(bf16)(ot[db][0] * inv), (bf16)(ot[db][1] * inv),
                        (bf16)(ot[db][2] * inv), (bf16)(ot[db][3] * inv)};
            *(bf16x4*)&ep[l16 * 72 + db * 16 + quad * 4] = w;
        }
        {
            const int orow = lane >> 2, oc = (lane & 3) * 16;  // 16 rows x 64 cols per wave
            bf16* Obase =
                O + ((size_t)(b * 2048 + q0 + wave * 16 + orow)) * 1024 + h * 64 + oc;
            const bf16* src = &ep[orow * 72 + oc];
            *(bf16x8*)&Obase[0] = *(const bf16x8*)&src[0];
            *(bf16x8*)&Obase[8] = *(const bf16x8*)&src[8];
        }
        __syncthreads();  // all KVs reads/epilogue done before next phase's staging
    }
}

extern "C" void kernel_launch(void* const* d_in, const int* in_sizes, int n_in,
                              void* d_out, int out_size, void* d_ws, size_t ws_size,
                              hipStream_t stream) {
    const float* x = (const float*)d_in[0];
    const float* Wq = (const float*)d_in[1];
    const float* bq = (const float*)d_in[2];
    const float* Wk = (const float*)d_in[3];
    const float* bk = (const float*)d_in[4];
    const float* Wv = (const float*)d_in[5];
    const float* bv = (const float*)d_in[6];
    float* out = (float*)d_out;

    const int M = 8192;  // B*T
    const size_t sz_x = (size_t)M * 1024;
    const size_t sz_w = (size_t)1024 * 1024;

    char* p = (char*)d_ws;
    bf16* xb = (bf16*)p;   p += sz_x * 2;
    bf16* Wcat = (bf16*)p; p += 3 * sz_w * 2;  // [Wq^T ; Wk^T ; Wv^T]
    bf16* qb = (bf16*)p;   p += sz_x * 2;
    bf16* kb = (bf16*)p;   p += sz_x * 2;
    bf16* Vt = (bf16*)p;   p += sz_x * 2;  // [B*H][64][2048]
    bf16* yatt = (bf16*)p; p += sz_x * 2;

    cvt_x<<<dim3(8192), dim3(256), 0, stream>>>(x, xb, (int)sz_x);
    transpose_w3<<<dim3(16, 16, 3), dim3(256), 0, stream>>>(Wq, Wk, Wv, Wcat);

    // fused QKV projection: [8192,1024] @ [1024,3072]
    gemm_bt<0><<<dim3(24, 64), dim3(256), 0, stream>>>(xb, Wcat, bq, bk, bv, qb, kb, Vt,
                                                       M, 3072, 1024);
    attn<<<dim3(16, 64), dim3(256), 0, stream>>>(qb, kb, Vt, yatt);
    // output projection (reference reuses v_proj): yatt @ Wv + bv -> f32 out
    gemm_bt<1><<<dim3(8, 64), dim3(256), 0, stream>>>(yatt, Wcat + 2 * sz_w, bv, bv, bv,
                                                      out, out, out, M, 1024, 1024);
}

// Round 2
// 268.638 us; speedup vs baseline: 1.1912x; 1.0631x over previous
//
#include <hip/hip_runtime.h>
#include <hip/hip_bf16.h>

typedef __bf16 bf16;
typedef __attribute__((ext_vector_type(8))) __bf16 bf16x8;
typedef __attribute__((ext_vector_type(4))) __bf16 bf16x4;
typedef __attribute__((ext_vector_type(2))) __bf16 bf16x2;
typedef __attribute__((ext_vector_type(4))) float f32x4;
typedef __attribute__((ext_vector_type(2))) unsigned int u32x2;
typedef __attribute__((ext_vector_type(4))) unsigned int u32x4;

#define MFMA16(a, b, c) __builtin_amdgcn_mfma_f32_16x16x32_bf16((a), (b), (c), 0, 0, 0)
#define SM_SCALE 0.18033688011112043f  // (1/8) * log2(e), folded into q at GEMM epilogue

__device__ __forceinline__ void gld_lds16(const bf16* g, bf16* l) {
    __builtin_amdgcn_global_load_lds((const __attribute__((address_space(1))) void*)g,
                                     (__attribute__((address_space(3))) void*)l, 16, 0, 0);
}

// raw barriers: no compiler-inserted vmcnt(0)/lgkmcnt(0) drain (that drain is the
// m97-structure stall). "memory" clobber pins LDS/global op ordering across them.
#define PBAR() asm volatile("s_barrier" ::: "memory")
#define VWAIT0() asm volatile("s_waitcnt vmcnt(0)" ::: "memory")

// ---------------- f32 -> bf16 convert (x) ----------------
__global__ __launch_bounds__(256) void cvt_x(const float* __restrict__ in,
                                             bf16* __restrict__ outb, int n) {
    int i = (blockIdx.x * 256 + threadIdx.x) * 4;
    if (i + 3 < n) {
        const float4 v = *(const float4*)(in + i);
        bf16x4 o = {(bf16)v.x, (bf16)v.y, (bf16)v.z, (bf16)v.w};
        *(bf16x4*)(outb + i) = o;
    }
}

// ---------------- W [K][N] f32 -> Wt [N][K] bf16, 3 weights in one launch ----------------
__global__ __launch_bounds__(256) void transpose_w3(const float* __restrict__ W0,
                                                    const float* __restrict__ W1,
                                                    const float* __restrict__ W2,
                                                    bf16* __restrict__ Wt) {
    const float* W = (blockIdx.z == 0) ? W0 : ((blockIdx.z == 1) ? W1 : W2);
    bf16* dst = Wt + (size_t)blockIdx.z * 1024 * 1024;
    __shared__ float tile[64][65];
    const int r0 = blockIdx.y * 64;  // k
    const int c0 = blockIdx.x * 64;  // n
    const int tid = threadIdx.x;
    for (int i = tid; i < 4096; i += 256) {
        int r = i >> 6, cc = i & 63;
        tile[r][cc] = W[(size_t)(r0 + r) * 1024 + c0 + cc];
    }
    __syncthreads();
    for (int i = tid; i < 4096; i += 256) {
        int n = i >> 6, k = i & 63;
        dst[(size_t)(c0 + n) * 1024 + r0 + k] = (bf16)tile[k][n];
    }
}

// ---------------- QKV GEMM: 256x256 tile, BK=64, 8 waves, 4-phase/K-tile ----------------
// C = A[8192,1024] @ Wcat[3072,1024]^T + bias, outputs q (pre-scaled), k, Vt (transposed).
// Schedule (provable): double-buffered K-tiles; stage(kt+1) issued at kt phase 0 into
// buf[1-p] (prior readers done before kt-1's closing barrier); sole vmcnt(0) at kt
// phase 3 (~3 phases after issue) + closing barrier publishes kt+1. T2 XOR-swizzle
// (byte ^= (row&7)<<4) applied stage-source-side + read-side (rule #21). T5 setprio
// around each 16-MFMA cluster.
#define QKV_PHASE(MH, COFF, READB)                                                        \
    {                                                                                     \
        if (READB) {                                                                      \
            _Pragma("unroll") for (int ni = 0; ni < 4; ni++) bfrag[ni] =                  \
                *(const bf16x8*)&Bsp[((wc * 64 + ni * 16 + l16) << 6) + (COFF)];          \
        }                                                                                 \
        bf16x8 af[4];                                                                     \
        _Pragma("unroll") for (int m4 = 0; m4 < 4; m4++) af[m4] =                         \
            *(const bf16x8*)&Asp[((wr * 128 + (MH)*64 + m4 * 16 + l16) << 6) + (COFF)];   \
        __builtin_amdgcn_s_setprio(1);                                                    \
        _Pragma("unroll") for (int m4 = 0; m4 < 4; m4++)                                  \
            _Pragma("unroll") for (int ni = 0; ni < 4; ni++) acc[(MH)*4 + m4][ni] =       \
                MFMA16(af[m4], bfrag[ni], acc[(MH)*4 + m4][ni]);                          \
        __builtin_amdgcn_s_setprio(0);                                                    \
    }

__global__ __launch_bounds__(512, 2) void gemm_qkv(const bf16* __restrict__ A,
                                                   const bf16* __restrict__ Bt,
                                                   const float* __restrict__ b0,
                                                   const float* __restrict__ b1,
                                                   const float* __restrict__ b2,
                                                   bf16* __restrict__ qb,
                                                   bf16* __restrict__ kb,
                                                   bf16* __restrict__ Vt) {
    __shared__ alignas(16) bf16 LDS[65536];  // 128 KiB: 2 bufs x (A 256x64 | B 256x64)

    // XCD-chunked bijective swizzle: 384 blocks, 48/XCD; chunk = 4 M-rows x all 12
    // N-cols -> A-panels (4 x 512 KB) L2-resident per XCD.
    const int orig = blockIdx.x;
    const int swz = (orig & 7) * 48 + (orig >> 3);
    const int by = swz / 12, bx = swz % 12;
    const int m0 = by * 256, n0 = bx * 256;

    const int tid = threadIdx.x;
    const int wid = tid >> 6, lane = tid & 63;
    const int wr = wid >> 2, wc = wid & 3;  // wave grid 2M x 4N; per-wave out 128x64
    const int quad = lane >> 4, l16 = lane & 15;

    // staging: thread covers rows sr+{0,64,128,192} of the 256-row tile, 16 B each,
    // source column pre-swizzled so linear LDS + XOR read yields logical data.
    const int sr = tid >> 3;
    const int scol = ((tid & 7) * 8) ^ ((sr & 7) * 8);
    const bf16* gA = A + (size_t)(m0 + sr) * 1024 + scol;
    const bf16* gB = Bt + (size_t)(n0 + sr) * 1024 + scol;
    bf16* lbase = &LDS[tid * 8];

    // read-side swizzled column offsets (full 6-bit XOR: ks*32 collides with xorE bit)
    const int xorE = (l16 & 7) * 8;
    const int coff0 = (quad * 8) ^ xorE;
    const int coff1 = (32 + quad * 8) ^ xorE;

    f32x4 acc[8][4] = {};
    bf16x8 bfrag[4];

    auto STAGE = [&](int kt, int p) {
        const bf16* a = gA + kt * 64;
        const bf16* b = gB + kt * 64;
        bf16* la = lbase + p * 32768;
        bf16* lb = la + 16384;
        gld_lds16(a, la);
        gld_lds16(a + 64 * 1024, la + 4096);
        gld_lds16(a + 128 * 1024, la + 8192);
        gld_lds16(a + 192 * 1024, la + 12288);
        gld_lds16(b, lb);
        gld_lds16(b + 64 * 1024, lb + 4096);
        gld_lds16(b + 128 * 1024, lb + 8192);
        gld_lds16(b + 192 * 1024, lb + 12288);
    };

    STAGE(0, 0);
    VWAIT0();
    PBAR();

#pragma unroll 1
    for (int kt = 0; kt < 16; kt++) {
        const int p = kt & 1;
        const bf16* Asp = &LDS[p * 32768];
        const bf16* Bsp = Asp + 16384;
        if (kt + 1 < 16) STAGE(kt + 1, p ^ 1);  // opposite buffer: free since kt-1's close
        QKV_PHASE(0, coff0, true);
        PBAR();
        QKV_PHASE(1, coff0, false);
        PBAR();
        QKV_PHASE(0, coff1, true);
        PBAR();
        QKV_PHASE(1, coff1, false);
        if (kt + 1 < 16) {
            VWAIT0();  // stage(kt+1) issued ~3 phases ago -> latency mostly hidden
            PBAR();    // closing barrier: publishes kt+1, releases buf[p]
        }
    }

    // epilogue
    const int sel = n0 >> 10;  // 0=q, 1=k, 2=v  (256 | 1024 -> never straddles)
    const int nl0 = (n0 & 1023) + wc * 64;
    const int mb0 = m0 + wr * 128;
    if (sel < 2) {
        const float* bias = (sel == 0) ? b0 : b1;
        bf16* Cp = (sel == 0) ? qb : kb;
        const float qs = (sel == 0) ? SM_SCALE : 1.0f;
#pragma unroll
        for (int mi = 0; mi < 8; mi++) {
            const int mbase = mb0 + mi * 16 + quad * 4;
#pragma unroll
            for (int ni = 0; ni < 4; ni++) {
                const int nl = nl0 + ni * 16 + l16;
                const float bv = bias[nl];
#pragma unroll
                for (int r = 0; r < 4; r++)
                    Cp[(size_t)(mbase + r) * 1024 + nl] = (bf16)((acc[mi][ni][r] + bv) * qs);
            }
        }
    } else {
        const int b = m0 >> 11;  // 2048 rows/batch; 256-row block never straddles
#pragma unroll
        for (int ni = 0; ni < 4; ni++) {
            const int nl = nl0 + ni * 16 + l16;
            const int h = nl >> 6, d = nl & 63;
            const float bv = b2[nl];
            bf16* dst = Vt + ((size_t)(b * 16 + h) * 64 + d) * 2048;
#pragma unroll
            for (int mi = 0; mi < 8; mi++) {
                const int t0 = (mb0 + mi * 16 + quad * 4) & 2047;  // batch-local t
                bf16x4 w = {(bf16)(acc[mi][ni][0] + bv), (bf16)(acc[mi][ni][1] + bv),
                            (bf16)(acc[mi][ni][2] + bv), (bf16)(acc[mi][ni][3] + bv)};
                *(bf16x4*)&dst[t0] = w;
            }
        }
    }
}

// ---------------- GEMM: C = A[M,K] @ Bt[N,K]^T + bias (output projection) ----------------
template <int MODE>
__global__ __launch_bounds__(256) void gemm_bt(const bf16* __restrict__ A,
                                               const bf16* __restrict__ Bt,
                                               const float* __restrict__ b0,
                                               void* __restrict__ out0,
                                               int M, int N, int K) {
    __shared__ alignas(16) bf16 As[128 * 32];
    __shared__ alignas(16) bf16 Bs[128 * 32];
    const int tid = threadIdx.x;
    const int wave = tid >> 6, lane = tid & 63;
    const int quad = lane >> 4, l16 = lane & 15;
    const int m0 = blockIdx.y * 128, n0 = blockIdx.x * 128;
    const int wm = (wave & 1) * 64, wn = (wave >> 1) * 64;

    f32x4 acc[4][4] = {};

    const int srow = lane >> 2, scol = (lane & 3) * 8;
    const bf16* ga = A + (size_t)(m0 + wave * 32 + srow) * K + scol;
    const bf16* gb = Bt + (size_t)(n0 + wave * 32 + srow) * K + scol;
    bf16* la = &As[(wave * 32) * 32];
    bf16* lb = &Bs[(wave * 32) * 32];

    for (int k0 = 0; k0 < K; k0 += 32) {
        __syncthreads();
        gld_lds16(ga + k0, la);
        gld_lds16(ga + k0 + (size_t)16 * K, la + 16 * 32);
        gld_lds16(gb + k0, lb);
        gld_lds16(gb + k0 + (size_t)16 * K, lb + 16 * 32);
        __syncthreads();
        bf16x8 af[4], bfr[4];
#pragma unroll
        for (int mi = 0; mi < 4; mi++)
            af[mi] = *(const bf16x8*)&As[(wm + mi * 16 + l16) * 32 + quad * 8];
#pragma unroll
        for (int ni = 0; ni < 4; ni++)
            bfr[ni] = *(const bf16x8*)&Bs[(wn + ni * 16 + l16) * 32 + quad * 8];
#pragma unroll
        for (int mi = 0; mi < 4; mi++)
#pragma unroll
            for (int ni = 0; ni < 4; ni++)
                acc[mi][ni] = MFMA16(af[mi], bfr[ni], acc[mi][ni]);
    }

    float* Cp = (float*)out0;
#pragma unroll
    for (int mi = 0; mi < 4; mi++) {
        const int mbase = m0 + wm + mi * 16 + quad * 4;
#pragma unroll
        for (int ni = 0; ni < 4; ni++) {
            const int n = n0 + wn + ni * 16 + l16;
            const float bv = b0[n];
#pragma unroll
            for (int r = 0; r < 4; r++)
                Cp[(size_t)(mbase + r) * 1024 + n] = acc[mi][ni][r] + bv;
        }
    }
}

// ---------------- flash attention, causal, hs=64 (R8 structure, unchanged) ----------------
template <bool NEEDMASK>
__device__ __forceinline__ void softmax_reg(const f32x4* st, float& l_i, bf16x8* pf,
                                            int qrel) {
    unsigned int p[4][2];
#pragma unroll
    for (int j = 0; j < 4; j++) {
        float pv[4];
#pragma unroll
        for (int r = 0; r < 4; r++) {
            float s = st[j][r];
            if (NEEDMASK && (j * 16 + r > qrel)) s = -1e30f;
            const float e = exp2f(s);
            l_i += e;
            pv[r] = e;
        }
        bf16x2 w0 = {(bf16)pv[0], (bf16)pv[1]};  // v_cvt_pk_bf16_f32 (compiler-fused)
        bf16x2 w1 = {(bf16)pv[2], (bf16)pv[3]};
        p[j][0] = __builtin_bit_cast(unsigned int, w0);
        p[j][1] = __builtin_bit_cast(unsigned int, w1);
    }
#pragma unroll
    for (int ks = 0; ks < 2; ks++) {
        unsigned int q4[4];
#pragma unroll
        for (int h = 0; h < 2; h++) {
            u32x2 s32 = __builtin_amdgcn_permlane32_swap(p[2 * ks][h], p[2 * ks + 1][h],
                                                         false, false);
            u32x2 s16 = __builtin_amdgcn_permlane16_swap(s32[0], s32[1], false, false);
            q4[h] = s16[0];      // e2 = h     (kv ofs 2h, 2h+1)
            q4[2 + h] = s16[1];  // e2 = 2+h   (kv ofs 4+2h, 5+2h)
        }
        u32x4 qq = {q4[0], q4[1], q4[2], q4[3]};
        pf[ks] = __builtin_bit_cast(bf16x8, qq);
    }
}

__global__ __launch_bounds__(256, 4) void attn(const bf16* __restrict__ Q,
                                               const bf16* __restrict__ Kg,
                                               const bf16* __restrict__ Vt,
                                               bf16* __restrict__ O) {
    const int lin = blockIdx.y * 16 + blockIdx.x;
    const int bh = (lin & 7) * 8 + ((lin >> 3) & 7);
    const int jb = lin >> 6;  // [0,16)
    const int b = bh >> 4, h = bh & 15;
    const int tid = threadIdx.x;
    const int wave = tid >> 6, lane = tid & 63;
    const int quad = lane >> 4, l16 = lane & 15;

    __shared__ alignas(16) bf16 KVs[2 * 128 * 72];  // dbuf; per buf: rows 0-63 K, 64-127 V^T

    const bf16* Kbase = Kg + ((size_t)b * 2048) * 1024 + h * 64;
    const bf16* Vbase = Vt + (size_t)bh * 64 * 2048;

    const int ra = tid >> 3, oa = (tid & 7) * 8;

#pragma unroll 1
    for (int phase = 0; phase < 2; phase++) {
        const int qs = (phase == 0) ? (31 - jb) : jb;
        const int q0 = qs * 64;
        const bf16* Qbase = Q + ((size_t)(b * 2048 + q0)) * 1024 + h * 64;

        bf16x8 qf[2];
#pragma unroll
        for (int ks = 0; ks < 2; ks++)
            qf[ks] = *(const bf16x8*)&Qbase[(size_t)(wave * 16 + l16) * 1024 + ks * 32 + quad * 8];

        float l_i = 0.f;
        f32x4 ot[4] = {};
        const int ntiles = qs + 1;
        const int qrel = wave * 16 + l16 - quad * 4;

        const bf16* pK0 = Kbase + (size_t)ra * 1024 + oa;
        const bf16* pK1 = Kbase + (size_t)(ra + 32) * 1024 + oa;
        const bf16* pV0 = Vbase + (size_t)ra * 2048 + oa;
        const bf16* pV1 = Vbase + (size_t)(ra + 32) * 2048 + oa;

        bf16x8 rc0 = *(const bf16x8*)pK0, rc1 = *(const bf16x8*)pK1;
        bf16x8 rc2 = *(const bf16x8*)pV0, rc3 = *(const bf16x8*)pV1;
        bf16x8 rn0, rn1, rn2, rn3;

#pragma unroll 1
        for (int tk = 0; tk < ntiles; tk++) {
            if (tk + 1 < ntiles) {
                rn0 = *(const bf16x8*)(pK0 + 64 * 1024);
                rn1 = *(const bf16x8*)(pK1 + 64 * 1024);
                rn2 = *(const bf16x8*)(pV0 + 64);
                rn3 = *(const bf16x8*)(pV1 + 64);
                pK0 += 64 * 1024; pK1 += 64 * 1024; pV0 += 64; pV1 += 64;
            }
            bf16* buf = &KVs[(tk & 1) * (128 * 72)];
            *(bf16x8*)&buf[ra * 72 + oa] = rc0;
            *(bf16x8*)&buf[(ra + 32) * 72 + oa] = rc1;
            *(bf16x8*)&buf[(64 + ra) * 72 + oa] = rc2;
            *(bf16x8*)&buf[(64 + ra + 32) * 72 + oa] = rc3;
            __syncthreads();

            f32x4 st[4] = {};
#pragma unroll
            for (int ks = 0; ks < 2; ks++)
#pragma unroll
                for (int j = 0; j < 4; j++) {
                    const bf16x8 kf =
                        *(const bf16x8*)&buf[(j * 16 + l16) * 72 + ks * 32 + quad * 8];
                    st[j] = MFMA16(kf, qf[ks], st[j]);
                }

            bf16x8 pf[2];
            if (tk == ntiles - 1)
                softmax_reg<true>(st, l_i, pf, qrel);
            else
                softmax_reg<false>(st, l_i, pf, qrel);

#pragma unroll
            for (int ks = 0; ks < 2; ks++)
#pragma unroll
                for (int db = 0; db < 4; db++) {
                    const bf16x8 vf =
                        *(const bf16x8*)&buf[(64 + db * 16 + l16) * 72 + ks * 32 + quad * 8];
                    ot[db] = MFMA16(vf, pf[ks], ot[db]);
                }
            rc0 = rn0; rc1 = rn1; rc2 = rn2; rc3 = rn3;
        }

        l_i += __shfl_xor(l_i, 16, 64);
        l_i += __shfl_xor(l_i, 32, 64);

        bf16* ep = &KVs[(ntiles & 1) * (128 * 72) + (wave * 16) * 72];
        const float inv = 1.f / l_i;
#pragma unroll
        for (int db = 0; db < 4; db++) {
            bf16x4 w = {(bf16)(ot[db][0] * inv), (bf16)(ot[db][1] * inv),
                        (bf16)(ot[db][2] * inv), (bf16)(ot[db][3] * inv)};
            *(bf16x4*)&ep[l16 * 72 + db * 16 + quad * 4] = w;
        }
        {
            const int orow = lane >> 2, oc = (lane & 3) * 16;
            bf16* Obase =
                O + ((size_t)(b * 2048 + q0 + wave * 16 + orow)) * 1024 + h * 64 + oc;
            const bf16* src = &ep[orow * 72 + oc];
            *(bf16x8*)&Obase[0] = *(const bf16x8*)&src[0];
            *(bf16x8*)&Obase[8] = *(const bf16x8*)&src[8];
        }
        __syncthreads();
    }
}

extern "C" void kernel_launch(void* const* d_in, const int* in_sizes, int n_in,
                              void* d_out, int out_size, void* d_ws, size_t ws_size,
                              hipStream_t stream) {
    const float* x = (const float*)d_in[0];
    const float* Wq = (const float*)d_in[1];
    const float* bq = (const float*)d_in[2];
    const float* Wk = (const float*)d_in[3];
    const float* bk = (const float*)d_in[4];
    const float* Wv = (const float*)d_in[5];
    const float* bv = (const float*)d_in[6];
    float* out = (float*)d_out;

    const int M = 8192;  // B*T
    const size_t sz_x = (size_t)M * 1024;
    const size_t sz_w = (size_t)1024 * 1024;

    char* p = (char*)d_ws;
    bf16* xb = (bf16*)p;   p += sz_x * 2;
    bf16* Wcat = (bf16*)p; p += 3 * sz_w * 2;  // [Wq^T ; Wk^T ; Wv^T]
    bf16* qb = (bf16*)p;   p += sz_x * 2;
    bf16* kb = (bf16*)p;   p += sz_x * 2;
    bf16* Vt = (bf16*)p;   p += sz_x * 2;  // [B*H][64][2048]
    bf16* yatt = (bf16*)p; p += sz_x * 2;

    cvt_x<<<dim3(8192), dim3(256), 0, stream>>>(x, xb, (int)sz_x);
    transpose_w3<<<dim3(16, 16, 3), dim3(256), 0, stream>>>(Wq, Wk, Wv, Wcat);

    // fused QKV projection: [8192,1024] @ [1024,3072] -- 256^2/8-wave phase-pipelined
    gemm_qkv<<<dim3(384), dim3(512), 0, stream>>>(xb, Wcat, bq, bk, bv, qb, kb, Vt);
    attn<<<dim3(16, 64), dim3(256), 0, stream>>>(qb, kb, Vt, yatt);
    // output projection (reference reuses v_proj): yatt @ Wv + bv -> f32 out
    gemm_bt<1><<<dim3(8, 64), dim3(256), 0, stream>>>(yatt, Wcat + 2 * sz_w, bv,
                                                      out, M, 1024, 1024);
}